// Round 1
// baseline (3358.990 us; speedup 1.0000x reference)
//
#include <hip/hip_runtime.h>

// MCH managed-collision remap: lower_bound binary search + gather + select.
// values:  [N]   int32 keys
// table:   [Z]   int32 sorted raw ids
// mapping: [Z]   int32 remapped ids
// zch:     [1]   int32 sentinel (= Z)
// out:     [N]   int32
//
// searchsorted(table[:-1], v, side='left') == lower_bound over idx in [0, Z-1)
// i.e. first idx with table[idx] >= v, clamped to Z-2+1 = Z-1 max.

__global__ __launch_bounds__(256) void mch_remap_kernel(
    const int* __restrict__ values,
    const int* __restrict__ table,
    const int* __restrict__ mapping,
    const int* __restrict__ zch_p,
    int* __restrict__ out,
    int n, int m /* = Z-1, search domain size */) {

    int i = blockIdx.x * blockDim.x + threadIdx.x;
    if (i >= n) return;

    int v = values[i];
    int lo = 0, hi = m;           // lower_bound over [0, m)
    while (lo < hi) {
        int mid = (lo + hi) >> 1;
        int t = table[mid];
        if (t < v) lo = mid + 1; else hi = mid;
    }
    // lo in [0, m] == [0, Z-1]; table[lo] always in-bounds (Z entries)
    int r = table[lo];
    int zch = *zch_p;
    out[i] = (r == v) ? mapping[lo] : zch;
}

extern "C" void kernel_launch(void* const* d_in, const int* in_sizes, int n_in,
                              void* d_out, int out_size, void* d_ws, size_t ws_size,
                              hipStream_t stream) {
    const int* values  = (const int*)d_in[0];
    const int* table   = (const int*)d_in[1];
    const int* mapping = (const int*)d_in[2];
    const int* zch_p   = (const int*)d_in[3];
    int* out = (int*)d_out;

    int n = in_sizes[0];          // 33_554_432
    int z = in_sizes[1];          // 4_194_304
    int m = z - 1;                // search over table[:-1]

    int block = 256;
    int grid = (n + block - 1) / block;
    mch_remap_kernel<<<grid, block, 0, stream>>>(values, table, mapping, zch_p, out, n, m);
}

// Round 2
// 2039.877 us; speedup vs baseline: 1.6467x; 1.6467x over previous
//
#include <hip/hip_runtime.h>

// MCH managed-collision remap: lower_bound + gather + select, via
// interpolation search (data is sorted-uniform; ~3-4 scattered probes
// instead of ~22 for bisection). Correct for ANY sorted input:
//  - bracket invariant: all idx < lo have table[idx] < v,
//    all idx >= hi have table[idx] >= v; answer in [lo, hi].
//  - interpolation capped at 8 iters, then pure bisection (termination).
//  - guess is clamped to [lo, hi-1]; guess quality affects speed only.

__global__ __launch_bounds__(256) void mch_remap_kernel(
    const int* __restrict__ values,
    const int* __restrict__ table,
    const int* __restrict__ mapping,
    const int* __restrict__ zch_p,
    int* __restrict__ out,
    int n, int m /* = Z-1, search domain size */) {

    int i = blockIdx.x * blockDim.x + threadIdx.x;
    if (i >= n) return;

    int v = values[i];

    int lo = 0, hi = m;                 // lower_bound over [0, m); answer in [lo, hi]
    float L = -1.0f;                    // table[lo-1] == L < v   (virtual at lo=0)
    float H = 2147483648.0f;            // table[hi]   == H >= v  (virtual at hi=m)
    float fv = (float)v;

    int iter = 0;
    while (hi - lo > 8) {
        int g;
        if (iter < 8) {
            // g = lo + span * (v - L) / (H - L), clamped into [lo, hi-1].
            float frac = (fv - L) / (H - L);
            g = lo + (int)((float)(hi - lo) * frac);
            if (g < lo) g = lo;
            if (g > hi - 1) g = hi - 1;
            ++iter;
        } else {
            g = (lo + hi) >> 1;         // guaranteed-progress fallback
        }
        int t = table[g];
        if (t < v) { lo = g + 1; L = (float)t; }
        else       { hi = g;     H = (float)t; }
    }

    // final window <= 8: sequential scan, 1-2 cache lines
    while (lo < hi && table[lo] < v) ++lo;

    int r = table[lo];                  // lo <= m = Z-1, always in-bounds
    int res;
    if (r == v) {
        res = mapping[lo];              // rare path (~0.2% of elements)
    } else {
        res = *zch_p;
    }
    out[i] = res;
}

extern "C" void kernel_launch(void* const* d_in, const int* in_sizes, int n_in,
                              void* d_out, int out_size, void* d_ws, size_t ws_size,
                              hipStream_t stream) {
    const int* values  = (const int*)d_in[0];
    const int* table   = (const int*)d_in[1];
    const int* mapping = (const int*)d_in[2];
    const int* zch_p   = (const int*)d_in[3];
    int* out = (int*)d_out;

    int n = in_sizes[0];          // 33_554_432
    int z = in_sizes[1];          // 4_194_304
    int m = z - 1;                // search over table[:-1]

    int block = 256;
    int grid = (n + block - 1) / block;
    mch_remap_kernel<<<grid, block, 0, stream>>>(values, table, mapping, zch_p, out, n, m);
}

// Round 3
// 1138.401 us; speedup vs baseline: 2.9506x; 1.7919x over previous
//
#include <hip/hip_runtime.h>

// MCH managed-collision remap via a precomputed L2-resident index:
//   aux[k] = lower_bound(table[:m], k << AUX_SH), k in [0, 2^AUX_BITS]
// For key v: k = v >> AUX_SH, answer in [aux[k], aux[k+1]] (expected width
// Z / 2^AUX_BITS = 8 entries). Resolve with a branchless count of entries < v
// over an int4-aligned span covering the bracket.
//
// Correctness invariants (hold for ANY sorted table):
//   idx <  aux[k]   => table[idx] <  (k<<SH)   <= v   (counted, all < v)
//   idx >= aux[k+1] => table[idx] >= ((k+1)<<SH) > v  (never counted)
// so  answer = s + |{idx in [s,e): table[idx] < v}|  for any aligned
// s <= aux[k], e >= aux[k+1];  hit iff some entry in [s,e) equals v.

#define AUX_BITS 19
#define AUX_SH   (31 - AUX_BITS)            // 12
#define AUX_N    ((1u << AUX_BITS) + 1u)    // 524289 entries (~2 MB)

__global__ __launch_bounds__(256) void build_aux_kernel(
    const int* __restrict__ table, int m, int* __restrict__ aux) {
    unsigned k = blockIdx.x * blockDim.x + threadIdx.x;
    if (k >= AUX_N) return;
    long long target = (long long)k << AUX_SH;
    int lo = 0, hi = m;                     // lower_bound over [0, m)
    while (lo < hi) {
        int mid = (lo + hi) >> 1;
        if ((long long)table[mid] < target) lo = mid + 1; else hi = mid;
    }
    aux[k] = lo;
}

__global__ __launch_bounds__(256) void mch_remap_aux_kernel(
    const int* __restrict__ values,
    const int* __restrict__ table,
    const int* __restrict__ mapping,
    const int* __restrict__ zch_p,
    const int* __restrict__ aux,
    int* __restrict__ out,
    int n, int z) {

    int zch = *zch_p;                       // uniform -> scalar load
    int i = blockIdx.x * blockDim.x + threadIdx.x;
    if (i >= n) return;

    int v = __builtin_nontemporal_load(values + i);
    unsigned k = ((unsigned)v) >> AUX_SH;   // v in [0, 2^31) -> k <= 2^19-1
    int lo = aux[k];
    int hi = aux[k + 1];

    int s = lo & ~3;                        // 16B-aligned start
    int e = (hi + 3) & ~3;                  // aligned end, >= hi
    if (e > z) e = z;                       // never OOB (entries in [hi,e) are >v anyway)

    int cnt = 0;
    bool eq = false;
    for (int p = s; p < e; p += 4) {
        int4 t = *(const int4*)(table + p);
        cnt += (t.x < v) + (t.y < v) + (t.z < v) + (t.w < v);
        eq = eq | (t.x == v) | (t.y == v) | (t.z == v) | (t.w == v);
    }
    int ans = s + cnt;                      // = lower_bound(table[:m], v)
    int res = eq ? mapping[ans] : zch;      // hit path is ~0.2% of lanes
    __builtin_nontemporal_store(res, out + i);
}

// Fallback (round-1 interpolation search) if ws is too small for aux.
__global__ __launch_bounds__(256) void mch_remap_interp_kernel(
    const int* __restrict__ values, const int* __restrict__ table,
    const int* __restrict__ mapping, const int* __restrict__ zch_p,
    int* __restrict__ out, int n, int m) {
    int i = blockIdx.x * blockDim.x + threadIdx.x;
    if (i >= n) return;
    int v = values[i];
    int lo = 0, hi = m;
    float L = -1.0f, H = 2147483648.0f, fv = (float)v;
    int iter = 0;
    while (hi - lo > 8) {
        int g;
        if (iter < 8) {
            float frac = (fv - L) / (H - L);
            g = lo + (int)((float)(hi - lo) * frac);
            if (g < lo) g = lo;
            if (g > hi - 1) g = hi - 1;
            ++iter;
        } else {
            g = (lo + hi) >> 1;
        }
        int t = table[g];
        if (t < v) { lo = g + 1; L = (float)t; } else { hi = g; H = (float)t; }
    }
    while (lo < hi && table[lo] < v) ++lo;
    int r = table[lo];
    out[i] = (r == v) ? mapping[lo] : *zch_p;
}

extern "C" void kernel_launch(void* const* d_in, const int* in_sizes, int n_in,
                              void* d_out, int out_size, void* d_ws, size_t ws_size,
                              hipStream_t stream) {
    const int* values  = (const int*)d_in[0];
    const int* table   = (const int*)d_in[1];
    const int* mapping = (const int*)d_in[2];
    const int* zch_p   = (const int*)d_in[3];
    int* out = (int*)d_out;

    int n = in_sizes[0];          // 33_554_432
    int z = in_sizes[1];          // 4_194_304
    int m = z - 1;                // search over table[:-1]

    size_t aux_bytes = (size_t)AUX_N * sizeof(int);
    if (ws_size >= aux_bytes) {
        int* aux = (int*)d_ws;
        int block = 256;
        int grid_b = (AUX_N + block - 1) / block;
        build_aux_kernel<<<grid_b, block, 0, stream>>>(table, m, aux);
        int grid = (n + block - 1) / block;
        mch_remap_aux_kernel<<<grid, block, 0, stream>>>(
            values, table, mapping, zch_p, aux, out, n, z);
    } else {
        int block = 256;
        int grid = (n + block - 1) / block;
        mch_remap_interp_kernel<<<grid, block, 0, stream>>>(
            values, table, mapping, zch_p, out, n, m);
    }
}

// Round 5
// 756.435 us; speedup vs baseline: 4.4406x; 1.5050x over previous
//
#include <hip/hip_runtime.h>

// MCH remap via an L3-resident bucket table: for k = v>>12 (2^19 buckets),
// bucket[k] is one 64 B record { base = lower_bound(table[:m], k<<12),
// t[0..14] = table[base..base+14] (INT_MAX-filled past end) }.
// Expected entries per 4096-wide key range = Z/2^19 = 8 (Poisson), so 15
// slots cover the bracket with P(overflow) ~ 0.4%; overflow (cnt==15)
// falls back to scanning the raw table from base+15.
//
// Correctness (any sorted table): entries < base are < k<<12 <= v; entries
// in the NEXT bucket are >= (k+1)<<12 > v, so counting "< v" over the 15
// slots gives the exact lower_bound offset whenever the first >=v entry is
// inside the bucket (cnt < 15). eq detects hits; ans is only used when eq.
// Domain end (search over table[:-1]): index m may appear in a bucket; eq
// on table[m] is exactly the reference's gather-and-compare semantics.

#define AUX_BITS 19
#define AUX_SH   (31 - AUX_BITS)            // 12
#define NBUCKET  (1u << AUX_BITS)           // 524288
#define AUX_N    (NBUCKET + 1u)

typedef int vint4 __attribute__((ext_vector_type(4)));  // nontemporal-capable

// ---- build step 1: aux[k] = lower_bound(table[:m], k<<SH), O(z) scatter ----
__global__ __launch_bounds__(256) void build_aux_scatter(
    const int* __restrict__ table, int m, int* __restrict__ aux) {
    int j = blockIdx.x * blockDim.x + threadIdx.x;
    if (j >= m) return;
    unsigned lo_k = (j == 0) ? 0u : ((((unsigned)table[j - 1]) >> AUX_SH) + 1u);
    unsigned hi_k = ((unsigned)table[j]) >> AUX_SH;
    for (unsigned k = lo_k; k <= hi_k; ++k) aux[k] = j;
    if (j == m - 1) {                        // tail: ranges above last entry
        for (unsigned k = hi_k + 1; k <= NBUCKET; ++k) aux[k] = m;
    }
}

// ---- build step 2: materialize 64 B buckets ----
__global__ __launch_bounds__(256) void build_buckets(
    const int* __restrict__ table, const int* __restrict__ aux, int z,
    int4* __restrict__ buckets) {
    unsigned k = blockIdx.x * blockDim.x + threadIdx.x;
    if (k >= NBUCKET) return;
    int base = aux[k];
    int t[15];
#pragma unroll
    for (int j = 0; j < 15; ++j) {
        int idx = base + j;
        t[j] = (idx < z) ? table[idx] : 0x7fffffff;
    }
    int4* b = buckets + 4 * (size_t)k;
    b[0] = make_int4(base, t[0], t[1], t[2]);
    b[1] = make_int4(t[3], t[4], t[5], t[6]);
    b[2] = make_int4(t[7], t[8], t[9], t[10]);
    b[3] = make_int4(t[11], t[12], t[13], t[14]);
}

// ---- main: 4 values/thread, one 64 B bucket line per value ----
__global__ __launch_bounds__(256) void mch_remap_bucket_kernel(
    const vint4* __restrict__ values4,
    const int* __restrict__ table,
    const int* __restrict__ mapping,
    const int* __restrict__ zch_p,
    const int4* __restrict__ buckets,
    vint4* __restrict__ out4,
    int n4, int z) {

    int zch = *zch_p;
    int i = blockIdx.x * blockDim.x + threadIdx.x;
    if (i >= n4) return;

    vint4 v4 = __builtin_nontemporal_load(values4 + i);
    int v[4] = {v4.x, v4.y, v4.z, v4.w};
    int res[4];

#pragma unroll
    for (int e = 0; e < 4; ++e) {
        unsigned k = ((unsigned)v[e]) >> AUX_SH;
        const int4* b = buckets + 4 * (size_t)k;
        int4 q0 = b[0], q1 = b[1], q2 = b[2], q3 = b[3];
        int base = q0.x;
        int t[15] = {q0.y, q0.z, q0.w,
                     q1.x, q1.y, q1.z, q1.w,
                     q2.x, q2.y, q2.z, q2.w,
                     q3.x, q3.y, q3.z, q3.w};
        int cnt = 0;
        bool eq = false;
#pragma unroll
        for (int j = 0; j < 15; ++j) {
            cnt += (t[j] < v[e]);
            eq = eq | (t[j] == v[e]);
        }
        int r;
        if (cnt == 15) {                     // rare: bracket exceeds bucket
            int p = base + 15;
            while (p < z && table[p] < v[e]) ++p;
            bool heq = (p < z) && (table[p] == v[e]);
            r = heq ? mapping[p] : zch;
        } else {
            r = eq ? mapping[base + cnt] : zch;   // hit path ~0.2% of lanes
        }
        res[e] = r;
    }
    vint4 o;
    o.x = res[0]; o.y = res[1]; o.z = res[2]; o.w = res[3];
    __builtin_nontemporal_store(o, out4 + i);
}

// scalar tail (n % 4 != 0) — same logic, one element per thread
__global__ __launch_bounds__(64) void mch_remap_tail_kernel(
    const int* __restrict__ values, const int* __restrict__ table,
    const int* __restrict__ mapping, const int* __restrict__ zch_p,
    const int4* __restrict__ buckets, int* __restrict__ out,
    int start, int n, int z) {
    int i = start + blockIdx.x * blockDim.x + threadIdx.x;
    if (i >= n) return;
    int v = values[i];
    unsigned k = ((unsigned)v) >> AUX_SH;
    const int4* b = buckets + 4 * (size_t)k;
    int4 q0 = b[0], q1 = b[1], q2 = b[2], q3 = b[3];
    int base = q0.x;
    int t[15] = {q0.y, q0.z, q0.w, q1.x, q1.y, q1.z, q1.w,
                 q2.x, q2.y, q2.z, q2.w, q3.x, q3.y, q3.z, q3.w};
    int cnt = 0; bool eq = false;
#pragma unroll
    for (int j = 0; j < 15; ++j) { cnt += (t[j] < v); eq = eq | (t[j] == v); }
    int r;
    if (cnt == 15) {
        int p = base + 15;
        while (p < z && table[p] < v) ++p;
        bool heq = (p < z) && (table[p] == v);
        r = heq ? mapping[p] : *zch_p;
    } else {
        r = eq ? mapping[base + cnt] : *zch_p;
    }
    out[i] = r;
}

// ---- fallback (round-2): aux-only windowed count, needs just ~2 MB ws ----
__global__ __launch_bounds__(256) void mch_remap_aux_kernel(
    const int* __restrict__ values, const int* __restrict__ table,
    const int* __restrict__ mapping, const int* __restrict__ zch_p,
    const int* __restrict__ aux, int* __restrict__ out, int n, int z) {
    int zch = *zch_p;
    int i = blockIdx.x * blockDim.x + threadIdx.x;
    if (i >= n) return;
    int v = __builtin_nontemporal_load(values + i);
    unsigned k = ((unsigned)v) >> AUX_SH;
    int lo = aux[k], hi = aux[k + 1];
    int s = lo & ~3;
    int e = (hi + 3) & ~3;
    if (e > z) e = z;
    int cnt = 0; bool eq = false;
    for (int p = s; p < e; p += 4) {
        int4 t = *(const int4*)(table + p);
        cnt += (t.x < v) + (t.y < v) + (t.z < v) + (t.w < v);
        eq = eq | (t.x == v) | (t.y == v) | (t.z == v) | (t.w == v);
    }
    int ans = s + cnt;
    out[i] = eq ? mapping[ans] : zch;
}

extern "C" void kernel_launch(void* const* d_in, const int* in_sizes, int n_in,
                              void* d_out, int out_size, void* d_ws, size_t ws_size,
                              hipStream_t stream) {
    const int* values  = (const int*)d_in[0];
    const int* table   = (const int*)d_in[1];
    const int* mapping = (const int*)d_in[2];
    const int* zch_p   = (const int*)d_in[3];
    int* out = (int*)d_out;

    int n = in_sizes[0];          // 33_554_432
    int z = in_sizes[1];          // 4_194_304
    int m = z - 1;

    size_t bucket_bytes = (size_t)NBUCKET * 64;
    size_t aux_bytes    = (size_t)AUX_N * sizeof(int);
    int block = 256;

    if (ws_size >= bucket_bytes + aux_bytes) {
        int4* buckets = (int4*)d_ws;
        int*  aux     = (int*)((char*)d_ws + bucket_bytes);

        build_aux_scatter<<<(m + block - 1) / block, block, 0, stream>>>(
            table, m, aux);
        build_buckets<<<(NBUCKET + block - 1) / block, block, 0, stream>>>(
            table, aux, z, buckets);

        int n4 = n >> 2;
        if (n4 > 0) {
            mch_remap_bucket_kernel<<<(n4 + block - 1) / block, block, 0, stream>>>(
                (const vint4*)values, table, mapping, zch_p, buckets,
                (vint4*)out, n4, z);
        }
        int tail = n & 3;
        if (tail) {
            mch_remap_tail_kernel<<<1, 64, 0, stream>>>(
                values, table, mapping, zch_p, buckets, out, n4 << 2, n, z);
        }
    } else if (ws_size >= aux_bytes) {
        int* aux = (int*)d_ws;
        build_aux_scatter<<<(m + block - 1) / block, block, 0, stream>>>(
            table, m, aux);
        mch_remap_aux_kernel<<<(n + block - 1) / block, block, 0, stream>>>(
            values, table, mapping, zch_p, aux, out, n, z);
    }
}

// Round 6
// 628.569 us; speedup vs baseline: 5.3439x; 1.2034x over previous
//
#include <hip/hip_runtime.h>

// MCH remap via L2-resident Bloom filter + aux-window exact resolution.
//
// Hit rate is Z/2^31 ~ 0.2%: almost every element maps to the zch sentinel.
// A 4 MB register-blocked Bloom filter (2^19 x 64-bit words, 4 bits/key,
// ~8 keys/word -> fp ~2.5-3%) fits in every XCD's 4 MB L2, so the common
// (negative) path costs ONE L2-resident 8 B probe and no scattered traffic.
// No false negatives (deterministic hash over all z table keys), so
// negatives are exactly zch. Positives (~3% = true hits + fp) resolve
// exactly with the round-2 scheme: aux[k] = lower_bound(table[:m], k<<12)
// (2 MB, L2-hot) brackets an ~8-entry window; a branchless count of
// "< v" over an int4-aligned span gives the exact lower_bound, eq detects
// true hits. Correctness invariants (any sorted table):
//   idx <  aux[k]   => table[idx] <  (k<<12)    <= v  (counted, all < v)
//   idx >= aux[k+1] => table[idx] >= (k+1)<<12  >  v  (never counted/eq)
// and if table[m] == v then aux[k+1] == m so index m is inside the window.

#define AUX_BITS 19
#define AUX_SH   (31 - AUX_BITS)            // 12
#define NBUCKET  (1u << AUX_BITS)           // 524288
#define AUX_N    (NBUCKET + 1u)

#define FBITS    19
#define FWORDS   (1u << FBITS)              // 512K u64 words = 4 MB
#define FMASK    (FWORDS - 1u)

typedef int vint4 __attribute__((ext_vector_type(4)));
typedef unsigned long long u64;

__device__ __forceinline__ u64 mixhash(unsigned v) {
    u64 h = (u64)v * 0x9E3779B97F4A7C15ULL;
    h ^= h >> 29;
    h *= 0xBF58476D1CE4E5B9ULL;
    h ^= h >> 32;
    return h;
}

__device__ __forceinline__ u64 bloom_mask(u64 h) {
    u64 m = (1ULL << ((h >> FBITS) & 63)) | (1ULL << ((h >> (FBITS + 6)) & 63));
    m |= (1ULL << ((h >> (FBITS + 12)) & 63)) | (1ULL << ((h >> (FBITS + 18)) & 63));
    return m;
}

// ---- zero the filter (ws is re-poisoned to 0xAA before every launch) ----
__global__ __launch_bounds__(256) void zero_filter(vint4* __restrict__ p, int n16) {
    int i = blockIdx.x * blockDim.x + threadIdx.x;
    int stride = gridDim.x * blockDim.x;
    vint4 zero = {0, 0, 0, 0};
    for (; i < n16; i += stride) p[i] = zero;
}

// ---- fused build: aux scatter (over table[:m]) + filter insert (table[:z]) ----
__global__ __launch_bounds__(256) void build_aux_filter(
    const int* __restrict__ table, int m, int z,
    int* __restrict__ aux, u64* __restrict__ filter) {
    int j = blockIdx.x * blockDim.x + threadIdx.x;
    if (j >= z) return;
    unsigned v = (unsigned)table[j];
    u64 h = mixhash(v);
    atomicOr(&filter[(unsigned)(h & FMASK)], bloom_mask(h));
    if (j < m) {
        unsigned lo_k = (j == 0) ? 0u : ((((unsigned)table[j - 1]) >> AUX_SH) + 1u);
        unsigned hi_k = v >> AUX_SH;
        for (unsigned k = lo_k; k <= hi_k; ++k) aux[k] = j;
        if (j == m - 1) {
            for (unsigned k = hi_k + 1; k <= NBUCKET; ++k) aux[k] = m;
        }
    }
}

// ---- exact resolution for filter-positive lanes (round-2 verified logic) ----
__device__ __forceinline__ int resolve_window(
    int v, const int* __restrict__ table, const int* __restrict__ mapping,
    const int* __restrict__ aux, int z, int zch) {
    unsigned k = ((unsigned)v) >> AUX_SH;
    int lo = aux[k];
    int hi = aux[k + 1];
    int s = lo & ~3;
    int e = (hi + 3) & ~3;
    if (e > z) e = z;
    int cnt = 0;
    bool eq = false;
    for (int p = s; p < e; p += 4) {
        int4 t = *(const int4*)(table + p);
        cnt += (t.x < v) + (t.y < v) + (t.z < v) + (t.w < v);
        eq = eq | (t.x == v) | (t.y == v) | (t.z == v) | (t.w == v);
    }
    return eq ? mapping[s + cnt] : zch;
}

// ---- main: 4 values/thread; Bloom probe; rare exact path ----
__global__ __launch_bounds__(256) void mch_remap_bloom_kernel(
    const vint4* __restrict__ values4,
    const int* __restrict__ table,
    const int* __restrict__ mapping,
    const int* __restrict__ zch_p,
    const int* __restrict__ aux,
    const u64* __restrict__ filter,
    vint4* __restrict__ out4,
    int n4, int z) {

    int zch = *zch_p;
    int i = blockIdx.x * blockDim.x + threadIdx.x;
    if (i >= n4) return;

    vint4 v4 = __builtin_nontemporal_load(values4 + i);
    int v[4] = {v4.x, v4.y, v4.z, v4.w};

    u64 h[4], w[4];
#pragma unroll
    for (int e = 0; e < 4; ++e) h[e] = mixhash((unsigned)v[e]);
#pragma unroll
    for (int e = 0; e < 4; ++e) w[e] = filter[(unsigned)(h[e] & FMASK)];

    int res[4];
#pragma unroll
    for (int e = 0; e < 4; ++e) {
        u64 mask = bloom_mask(h[e]);
        bool maybe = (w[e] & mask) == mask;      // ~3% of lanes
        res[e] = maybe ? resolve_window(v[e], table, mapping, aux, z, zch)
                       : zch;
    }
    vint4 o;
    o.x = res[0]; o.y = res[1]; o.z = res[2]; o.w = res[3];
    __builtin_nontemporal_store(o, out4 + i);
}

// scalar tail (n % 4 != 0)
__global__ __launch_bounds__(64) void mch_remap_tail_kernel(
    const int* __restrict__ values, const int* __restrict__ table,
    const int* __restrict__ mapping, const int* __restrict__ zch_p,
    const int* __restrict__ aux, const u64* __restrict__ filter,
    int* __restrict__ out, int start, int n, int z) {
    int i = start + blockIdx.x * blockDim.x + threadIdx.x;
    if (i >= n) return;
    int v = values[i];
    u64 h = mixhash((unsigned)v);
    u64 w = filter[(unsigned)(h & FMASK)];
    u64 mask = bloom_mask(h);
    int zch = *zch_p;
    out[i] = ((w & mask) == mask)
                 ? resolve_window(v, table, mapping, aux, z, zch) : zch;
}

// ---- fallback (round-2): aux-only windowed count, ~2 MB ws ----
__global__ __launch_bounds__(256) void mch_remap_aux_kernel(
    const int* __restrict__ values, const int* __restrict__ table,
    const int* __restrict__ mapping, const int* __restrict__ zch_p,
    const int* __restrict__ aux, int* __restrict__ out, int n, int z) {
    int zch = *zch_p;
    int i = blockIdx.x * blockDim.x + threadIdx.x;
    if (i >= n) return;
    int v = __builtin_nontemporal_load(values + i);
    out[i] = resolve_window(v, table, mapping, aux, z, zch);
}

__global__ __launch_bounds__(256) void build_aux_scatter(
    const int* __restrict__ table, int m, int* __restrict__ aux) {
    int j = blockIdx.x * blockDim.x + threadIdx.x;
    if (j >= m) return;
    unsigned lo_k = (j == 0) ? 0u : ((((unsigned)table[j - 1]) >> AUX_SH) + 1u);
    unsigned hi_k = ((unsigned)table[j]) >> AUX_SH;
    for (unsigned k = lo_k; k <= hi_k; ++k) aux[k] = j;
    if (j == m - 1) {
        for (unsigned k = hi_k + 1; k <= NBUCKET; ++k) aux[k] = m;
    }
}

extern "C" void kernel_launch(void* const* d_in, const int* in_sizes, int n_in,
                              void* d_out, int out_size, void* d_ws, size_t ws_size,
                              hipStream_t stream) {
    const int* values  = (const int*)d_in[0];
    const int* table   = (const int*)d_in[1];
    const int* mapping = (const int*)d_in[2];
    const int* zch_p   = (const int*)d_in[3];
    int* out = (int*)d_out;

    int n = in_sizes[0];          // 33_554_432
    int z = in_sizes[1];          // 4_194_304
    int m = z - 1;

    size_t filter_bytes = (size_t)FWORDS * 8;            // 4 MB
    size_t aux_bytes    = (size_t)AUX_N * sizeof(int);   // ~2 MB
    int block = 256;

    if (ws_size >= filter_bytes + aux_bytes) {
        u64* filter = (u64*)d_ws;
        int* aux    = (int*)((char*)d_ws + filter_bytes);

        int n16 = (int)(filter_bytes / 16);
        zero_filter<<<1024, block, 0, stream>>>((vint4*)filter, n16);
        build_aux_filter<<<(z + block - 1) / block, block, 0, stream>>>(
            table, m, z, aux, filter);

        int n4 = n >> 2;
        if (n4 > 0) {
            mch_remap_bloom_kernel<<<(n4 + block - 1) / block, block, 0, stream>>>(
                (const vint4*)values, table, mapping, zch_p, aux, filter,
                (vint4*)out, n4, z);
        }
        int tail = n & 3;
        if (tail) {
            mch_remap_tail_kernel<<<1, 64, 0, stream>>>(
                values, table, mapping, zch_p, aux, filter, out, n4 << 2, n, z);
        }
    } else if (ws_size >= aux_bytes) {
        int* aux = (int*)d_ws;
        build_aux_scatter<<<(m + block - 1) / block, block, 0, stream>>>(
            table, m, aux);
        mch_remap_aux_kernel<<<(n + block - 1) / block, block, 0, stream>>>(
            values, table, mapping, zch_p, aux, out, n, z);
    }
}

// Round 7
// 504.337 us; speedup vs baseline: 6.6602x; 1.2463x over previous
//
#include <hip/hip_runtime.h>

// MCH remap via cell-indexed Bloom signatures + aux-window exact resolution.
//
// Hit rate ~0.2%. For cell k = v>>12 (2^19 cells), filter[k] is a 64-bit
// Bloom signature of the ~8 table keys in that cell (4 hashed bits/key,
// fp ~3%). filter is 4 MB -> L2-resident; the common negative path costs
// one 8 B L2 load, no scattered traffic. Because cells partition the SORTED
// table, the build needs no atomics: aux[k] = lower_bound(table[:m], k<<12)
// (scatter, no atomics), then one thread per cell reads its contiguous
// entries and plain-stores the signature (covers index m too, since it
// scans while table[p]>>12 == k, p < z).
//
// Positives (~3%) resolve exactly (round-2 verified logic): window
// [aux[k], aux[k+1]) extended to int4 alignment; count "< v" gives the
// lower_bound, eq detects true hits. Invariants (any sorted table):
//   idx <  aux[k]   => table[idx] <  (k<<12)    <= v  (counted, all < v)
//   idx >= aux[k+1] => table[idx] >= (k+1)<<12  >  v  (never counted/eq)
// and if table[m] == v the clamped-to-z window includes index m.

#define AUX_BITS 19
#define AUX_SH   (31 - AUX_BITS)            // 12
#define NBUCKET  (1u << AUX_BITS)           // 524288
#define AUX_N    (NBUCKET + 1u)

typedef int vint4 __attribute__((ext_vector_type(4)));
typedef unsigned long long u64;

#define HK 2654435761u                      // Knuth multiplicative hash

__device__ __forceinline__ u64 sig_mask(unsigned v) {
    unsigned h = v * HK;                    // bits 8..31 used, disjoint 6-bit fields
    return (1ULL << (h >> 26)) | (1ULL << ((h >> 20) & 63)) |
           (1ULL << ((h >> 14) & 63)) | (1ULL << ((h >> 8) & 63));
}

// ---- build 1: aux[k] = lower_bound(table[:m], k<<SH), O(z) scatter ----
__global__ __launch_bounds__(256) void build_aux_scatter(
    const int* __restrict__ table, int m, int* __restrict__ aux) {
    int j = blockIdx.x * blockDim.x + threadIdx.x;
    if (j >= m) return;
    unsigned lo_k = (j == 0) ? 0u : ((((unsigned)table[j - 1]) >> AUX_SH) + 1u);
    unsigned hi_k = ((unsigned)table[j]) >> AUX_SH;
    for (unsigned k = lo_k; k <= hi_k; ++k) aux[k] = j;
    if (j == m - 1) {
        for (unsigned k = hi_k + 1; k <= NBUCKET; ++k) aux[k] = m;
    }
}

// ---- build 2: per-cell signature, sequential reads, plain store ----
__global__ __launch_bounds__(256) void build_sigs(
    const int* __restrict__ table, const int* __restrict__ aux, int z,
    u64* __restrict__ filter) {
    unsigned k = blockIdx.x * blockDim.x + threadIdx.x;
    if (k >= NBUCKET) return;
    int p = aux[k];
    u64 sig = 0;
    while (p < z && ((((unsigned)table[p]) >> AUX_SH) == k)) {
        sig |= sig_mask((unsigned)table[p]);
        ++p;
    }
    filter[k] = sig;
}

// ---- exact resolution for filter-positive lanes ----
__device__ __forceinline__ int resolve_window(
    int v, const int* __restrict__ table, const int* __restrict__ mapping,
    const int* __restrict__ aux, int z, int zch) {
    unsigned k = ((unsigned)v) >> AUX_SH;
    int lo = aux[k];
    int hi = aux[k + 1];
    int s = lo & ~3;
    int e = (hi + 3) & ~3;
    if (e > z) e = z;
    int cnt = 0;
    bool eq = false;
    for (int p = s; p < e; p += 4) {
        int4 t = *(const int4*)(table + p);
        cnt += (t.x < v) + (t.y < v) + (t.z < v) + (t.w < v);
        eq = eq | (t.x == v) | (t.y == v) | (t.z == v) | (t.w == v);
    }
    return eq ? mapping[s + cnt] : zch;
}

// ---- main: 8 values/thread (two coalesced int4 segments) ----
__global__ __launch_bounds__(256) void mch_remap_bloom_kernel(
    const vint4* __restrict__ values4,
    const int* __restrict__ table,
    const int* __restrict__ mapping,
    const int* __restrict__ zch_p,
    const int* __restrict__ aux,
    const u64* __restrict__ filter,
    vint4* __restrict__ out4,
    int half4, int z) {

    int zch = *zch_p;
    int i = blockIdx.x * blockDim.x + threadIdx.x;
    if (i >= half4) return;

    vint4 va = __builtin_nontemporal_load(values4 + i);
    vint4 vb = __builtin_nontemporal_load(values4 + i + half4);
    int v[8] = {va.x, va.y, va.z, va.w, vb.x, vb.y, vb.z, vb.w};

    u64 w[8];
#pragma unroll
    for (int e = 0; e < 8; ++e) w[e] = filter[((unsigned)v[e]) >> AUX_SH];

    int res[8];
#pragma unroll
    for (int e = 0; e < 8; ++e) {
        u64 mask = sig_mask((unsigned)v[e]);
        bool maybe = (w[e] & mask) == mask;      // ~3% of lanes
        res[e] = maybe ? resolve_window(v[e], table, mapping, aux, z, zch)
                       : zch;
    }
    vint4 oa, ob;
    oa.x = res[0]; oa.y = res[1]; oa.z = res[2]; oa.w = res[3];
    ob.x = res[4]; ob.y = res[5]; ob.z = res[6]; ob.w = res[7];
    __builtin_nontemporal_store(oa, out4 + i);
    __builtin_nontemporal_store(ob, out4 + i + half4);
}

// scalar tail (n % 8 != 0)
__global__ __launch_bounds__(64) void mch_remap_tail_kernel(
    const int* __restrict__ values, const int* __restrict__ table,
    const int* __restrict__ mapping, const int* __restrict__ zch_p,
    const int* __restrict__ aux, const u64* __restrict__ filter,
    int* __restrict__ out, int start, int n, int z) {
    int i = start + blockIdx.x * blockDim.x + threadIdx.x;
    if (i >= n) return;
    int v = values[i];
    u64 w = filter[((unsigned)v) >> AUX_SH];
    u64 mask = sig_mask((unsigned)v);
    int zch = *zch_p;
    out[i] = ((w & mask) == mask)
                 ? resolve_window(v, table, mapping, aux, z, zch) : zch;
}

// ---- fallback (round-2): aux-only windowed count, ~2 MB ws ----
__global__ __launch_bounds__(256) void mch_remap_aux_kernel(
    const int* __restrict__ values, const int* __restrict__ table,
    const int* __restrict__ mapping, const int* __restrict__ zch_p,
    const int* __restrict__ aux, int* __restrict__ out, int n, int z) {
    int zch = *zch_p;
    int i = blockIdx.x * blockDim.x + threadIdx.x;
    if (i >= n) return;
    int v = __builtin_nontemporal_load(values + i);
    out[i] = resolve_window(v, table, mapping, aux, z, zch);
}

extern "C" void kernel_launch(void* const* d_in, const int* in_sizes, int n_in,
                              void* d_out, int out_size, void* d_ws, size_t ws_size,
                              hipStream_t stream) {
    const int* values  = (const int*)d_in[0];
    const int* table   = (const int*)d_in[1];
    const int* mapping = (const int*)d_in[2];
    const int* zch_p   = (const int*)d_in[3];
    int* out = (int*)d_out;

    int n = in_sizes[0];          // 33_554_432
    int z = in_sizes[1];          // 4_194_304
    int m = z - 1;

    size_t filter_bytes = (size_t)NBUCKET * 8;           // 4 MB
    size_t aux_bytes    = (size_t)AUX_N * sizeof(int);   // ~2 MB
    int block = 256;

    if (ws_size >= filter_bytes + aux_bytes) {
        u64* filter = (u64*)d_ws;
        int* aux    = (int*)((char*)d_ws + filter_bytes);

        build_aux_scatter<<<(m + block - 1) / block, block, 0, stream>>>(
            table, m, aux);
        build_sigs<<<(NBUCKET + block - 1) / block, block, 0, stream>>>(
            table, aux, z, filter);

        int half4 = n >> 3;                  // int4 units per segment
        if (half4 > 0) {
            mch_remap_bloom_kernel<<<(half4 + block - 1) / block, block, 0, stream>>>(
                (const vint4*)values, table, mapping, zch_p, aux, filter,
                (vint4*)out, half4, z);
        }
        int done = (half4 << 3);
        if (done < n) {
            mch_remap_tail_kernel<<<((n - done) + 63) / 64, 64, 0, stream>>>(
                values, table, mapping, zch_p, aux, filter, out, done, n, z);
        }
    } else if (ws_size >= aux_bytes) {
        int* aux = (int*)d_ws;
        build_aux_scatter<<<(m + block - 1) / block, block, 0, stream>>>(
            table, m, aux);
        mch_remap_aux_kernel<<<(n + block - 1) / block, block, 0, stream>>>(
            values, table, mapping, zch_p, aux, out, n, z);
    }
}